// Round 4
// baseline (109.963 us; speedup 1.0000x reference)
//
#include <hip/hip_runtime.h>
#include <hip/hip_bf16.h>

typedef __attribute__((ext_vector_type(8))) __bf16 bf16x8;
typedef __attribute__((ext_vector_type(4))) float f32x4;
typedef __attribute__((ext_vector_type(4))) unsigned short u16x4;
typedef unsigned short u16;

typedef __attribute__((address_space(1))) void gvoid;
typedef __attribute__((address_space(3))) void lvoid;

#define B_DIM 8192
#define H_DIM 512

#define MFMA(a, b, c) __builtin_amdgcn_mfma_f32_16x16x32_bf16((a), (b), (c), 0, 0, 0)
#define WAITVM(N) asm volatile("s_waitcnt vmcnt(" #N ")" ::: "memory")

__device__ __forceinline__ u16x4 cvt4(f32x4 v) {
    u16x4 r;
    r.x = __builtin_bit_cast(u16, __float2bfloat16(v.x));
    r.y = __builtin_bit_cast(u16, __float2bfloat16(v.y));
    r.z = __builtin_bit_cast(u16, __float2bfloat16(v.z));
    r.w = __builtin_bit_cast(u16, __float2bfloat16(v.w));
    return r;
}

// Stage a 128x64 bf16 tile into LDS (512 threads, 2 x 16B per thread).
// LDS dest linear (global_load_lds requirement); global SOURCE column pre-
// permuted: LDS slot s of row r holds global slot s^(r&7). Readers apply the
// same XOR (ld_frag). [rule #21 both-sides]
__device__ __forceinline__ void stage128(const u16* g, int ldg, u16* ls, int t) {
#pragma unroll
    for (int it = 0; it < 2; ++it) {
        int e = it * 4096 + t * 8;
        int r = e >> 6;
        int slot = (e & 63) >> 3;
        int csrc = (slot ^ (r & 7)) << 3;
        __builtin_amdgcn_global_load_lds((gvoid*)(g + (size_t)r * ldg + csrc),
                                         (lvoid*)&ls[e], 16, 0, 0);
    }
}

__device__ __forceinline__ bf16x8 ld_frag(const u16* ls, int row, int kslot) {
    return *(const bf16x8*)&ls[row * 64 + ((kslot ^ (row & 7)) << 3)];
}

// ---------------- all_zero flag ----------------
__global__ void k_flag(const int* __restrict__ pd, int* __restrict__ flag) {
    __shared__ int s;
    if (threadIdx.x == 0) s = 0;
    __syncthreads();
    int any = 0;
    for (int i = threadIdx.x; i < B_DIM; i += 1024) any |= pd[i];
    if (any) atomicOr(&s, 1);
    __syncthreads();
    if (threadIdx.x == 0) flag[0] = (s == 0) ? 1 : 0;
}

// ---------------- fused prep ----------------
__global__ void k_prep2(const float* __restrict__ X, const float* __restrict__ prev_a,
                        const float* __restrict__ prev_b, const int* __restrict__ prev_depth,
                        const float* __restrict__ w_f, const int* __restrict__ flag,
                        u16* __restrict__ Xb, u16* __restrict__ pab,
                        u16* __restrict__ pb0b, u16* __restrict__ pb1b,
                        float* __restrict__ coeffs, float* __restrict__ outA,
                        float* __restrict__ outB, float* __restrict__ outD,
                        float* __restrict__ outF, float* __restrict__ outJ) {
    int wv = threadIdx.x >> 6, l = threadIdx.x & 63;
    int row = blockIdx.x * 4 + wv;
    size_t r512 = (size_t)row * 512, r1024 = (size_t)row * 1024;
    int i = l * 8;
    f32x4 x0  = *(const f32x4*)(X + r512 + i);
    f32x4 x1  = *(const f32x4*)(X + r512 + i + 4);
    f32x4 pa0 = *(const f32x4*)(prev_a + r1024 + 512 + i);
    f32x4 pa1 = *(const f32x4*)(prev_a + r1024 + 512 + i + 4);
    f32x4 q00 = *(const f32x4*)(prev_b + r1024 + i);
    f32x4 q01 = *(const f32x4*)(prev_b + r1024 + i + 4);
    f32x4 q10 = *(const f32x4*)(prev_b + r1024 + 512 + i);
    f32x4 q11 = *(const f32x4*)(prev_b + r1024 + 512 + i + 4);
    f32x4 w0  = *(const f32x4*)(w_f + i);
    f32x4 w1  = *(const f32x4*)(w_f + i + 4);
    int depth = prev_depth[row];
    f32x4 b0 = depth ? q10 : q00;
    f32x4 b1 = depth ? q11 : q01;
    float dot = b0.x*w0.x + b0.y*w0.y + b0.z*w0.z + b0.w*w0.w
              + b1.x*w1.x + b1.y*w1.y + b1.z*w1.z + b1.w*w1.w;
    for (int off = 32; off > 0; off >>= 1) dot += __shfl_xor(dot, off, 64);

    *(u16x4*)(Xb   + r512 + i)     = cvt4(x0);
    *(u16x4*)(Xb   + r512 + i + 4) = cvt4(x1);
    *(u16x4*)(pab  + r512 + i)     = cvt4(pa0);
    *(u16x4*)(pab  + r512 + i + 4) = cvt4(pa1);
    *(u16x4*)(pb0b + r512 + i)     = cvt4(q00);
    *(u16x4*)(pb0b + r512 + i + 4) = cvt4(q01);
    *(u16x4*)(pb1b + r512 + i)     = cvt4(q10);
    *(u16x4*)(pb1b + r512 + i + 4) = cvt4(q11);
    f32x4 z; z.x = 0.f; z.y = 0.f; z.z = 0.f; z.w = 0.f;
    *(f32x4*)(outA + r1024 + i)     = z;
    *(f32x4*)(outA + r1024 + i + 4) = z;
    *(f32x4*)(outB + r1024 + i)     = z;
    *(f32x4*)(outB + r1024 + i + 4) = z;

    if (l == 0) {
        int az = flag[0];
        float sg = 1.0f / (1.0f + expf(-dot));
        float fr = rintf(sg);
        float f = az ? 1.0f : fr;
        float j = az ? 0.0f : fr;
        int nd = depth + (int)(f - j);
        float eq = (nd == 1) ? 1.0f : 0.0f;
        float lt = (nd < 1) ? 1.0f : 0.0f;
        f32x4 c; c.x = eq * (f * j); c.y = eq * (1.0f - f) * (1.0f - j);
        c.z = eq * f * (1.0f - j); c.w = lt;
        *(f32x4*)(coeffs + (size_t)row * 4) = c;
        outD[row] = (float)nd;
        outF[row] = f;
        outJ[row] = j;
    }
}

// ---------------- convert all 5 weight matrices to bf16 ----------------
__global__ void k_conv_w(const float* __restrict__ wa00, const float* __restrict__ wa10,
                         const float* __restrict__ wb00, const float* __restrict__ wb11,
                         const float* __restrict__ wb10,
                         u16* __restrict__ oa00, u16* __restrict__ oa10,
                         u16* __restrict__ ob00, u16* __restrict__ ob11,
                         u16* __restrict__ ob10) {
    int t = blockIdx.x * 256 + threadIdx.x;
    const int S  = 512 * 1024 / 4;
    const int SB = 512 * 1536 / 4;
    const float* src; u16* dst; int off;
    if      (t < S)            { src = wa00; dst = oa00; off = t; }
    else if (t < 2 * S)        { src = wa10; dst = oa10; off = t - S; }
    else if (t < 2 * S + SB)   { src = wb00; dst = ob00; off = t - 2 * S; }
    else if (t < 3 * S + SB)   { src = wb11; dst = ob11; off = t - 2 * S - SB; }
    else if (t < 4 * S + SB)   { src = wb10; dst = ob10; off = t - 3 * S - SB; }
    else return;
    f32x4 v = *(const f32x4*)(src + (size_t)off * 4);
    *(u16x4*)(dst + (size_t)off * 4) = cvt4(v);
}

// ---------------- phase-1 fused GEMM (pipelined): a00 & a10 + epilogue A ----------------
// 256 blocks (128x128 tile), 512 threads = 8 waves (2M x 4N), per-wave 64x32.
// Double-buffered LDS, counted-vmcnt raw-barrier pipeline (T3/T4 minimum recipe).
__global__ __launch_bounds__(512, 2) void k_gemmA(
    const u16* __restrict__ Xb, const u16* __restrict__ pab, const u16* __restrict__ pb0b,
    const u16* __restrict__ w0, const u16* __restrict__ w1,
    const float* __restrict__ prev_a, const float* __restrict__ coeffs,
    float* __restrict__ outA, u16* __restrict__ na1b)
{
    __shared__ u16 lds[2][3][8192];   // per buffer: A + 2 B tiles (48 KB); dbuf 96 KB
    const int t = threadIdx.x;
    int raw = (int)blockIdx.x;
    int bid = (raw & 7) * 32 + (raw >> 3);        // XCD-contiguous chunks (256/8=32)
    const int m0 = (bid >> 2) * 128;
    const int n0 = (bid & 3) * 128;
    const int lane = t & 63, wv = t >> 6;
    const int wr = (wv >> 2) * 64, wc = (wv & 3) * 32;
    const int fr = lane & 15, fq = lane >> 4;

    f32x4 acc0[4][2] = {}, acc1[4][2] = {};

    auto stage_step = [&](int s, u16 (*buf)[8192]) {
        int cb = (s & 7) * 64;
        int seg = s >> 3;
        if (seg == 0) {                 // A = X; B = w0, w1 (low K)   6 loads/thr
            stage128(Xb + (size_t)m0 * 512 + cb, 512, buf[0], t);
            stage128(w0 + (size_t)n0 * 1024 + cb, 1024, buf[1], t);
            stage128(w1 + (size_t)n0 * 1024 + cb, 1024, buf[2], t);
        } else if (seg == 1) {          // A = pa; B = w0 (high K)     4 loads/thr
            stage128(pab + (size_t)m0 * 512 + cb, 512, buf[0], t);
            stage128(w0 + (size_t)n0 * 1024 + 512 + cb, 1024, buf[1], t);
        } else {                        // A = pb0; B = w1 (high K)    4 loads/thr
            stage128(pb0b + (size_t)m0 * 512 + cb, 512, buf[0], t);
            stage128(w1 + (size_t)n0 * 1024 + 512 + cb, 1024, buf[1], t);
        }
    };

    stage_step(0, lds[0]);
    for (int s = 0; s < 24; ++s) {
        int cur = s & 1;
        if (s + 1 < 24) {
            stage_step(s + 1, lds[cur ^ 1]);
            if ((s + 1) >> 3 == 0) WAITVM(6); else WAITVM(4);
        } else {
            WAITVM(0);
        }
        __builtin_amdgcn_s_barrier();
        asm volatile("" ::: "memory");
        u16 (*buf)[8192] = lds[cur];
        int seg = s >> 3;
        if (seg == 0) {
#pragma unroll
            for (int kk = 0; kk < 2; ++kk) {
                int ks = kk * 4 + fq;
                bf16x8 a[4], b0[2], b1[2];
#pragma unroll
                for (int mi = 0; mi < 4; ++mi) a[mi] = ld_frag(buf[0], wr + mi * 16 + fr, ks);
#pragma unroll
                for (int ni = 0; ni < 2; ++ni) {
                    b0[ni] = ld_frag(buf[1], wc + ni * 16 + fr, ks);
                    b1[ni] = ld_frag(buf[2], wc + ni * 16 + fr, ks);
                }
#pragma unroll
                for (int mi = 0; mi < 4; ++mi)
#pragma unroll
                    for (int ni = 0; ni < 2; ++ni) {
                        acc0[mi][ni] = MFMA(a[mi], b0[ni], acc0[mi][ni]);
                        acc1[mi][ni] = MFMA(a[mi], b1[ni], acc1[mi][ni]);
                    }
            }
        } else if (seg == 1) {
#pragma unroll
            for (int kk = 0; kk < 2; ++kk) {
                int ks = kk * 4 + fq;
                bf16x8 a[4], b0[2];
#pragma unroll
                for (int mi = 0; mi < 4; ++mi) a[mi] = ld_frag(buf[0], wr + mi * 16 + fr, ks);
#pragma unroll
                for (int ni = 0; ni < 2; ++ni) b0[ni] = ld_frag(buf[1], wc + ni * 16 + fr, ks);
#pragma unroll
                for (int mi = 0; mi < 4; ++mi)
#pragma unroll
                    for (int ni = 0; ni < 2; ++ni)
                        acc0[mi][ni] = MFMA(a[mi], b0[ni], acc0[mi][ni]);
            }
        } else {
#pragma unroll
            for (int kk = 0; kk < 2; ++kk) {
                int ks = kk * 4 + fq;
                bf16x8 a[4], b0[2];
#pragma unroll
                for (int mi = 0; mi < 4; ++mi) a[mi] = ld_frag(buf[0], wr + mi * 16 + fr, ks);
#pragma unroll
                for (int ni = 0; ni < 2; ++ni) b0[ni] = ld_frag(buf[1], wc + ni * 16 + fr, ks);
#pragma unroll
                for (int mi = 0; mi < 4; ++mi)
#pragma unroll
                    for (int ni = 0; ni < 2; ++ni)
                        acc1[mi][ni] = MFMA(a[mi], b0[ni], acc1[mi][ni]);
            }
        }
        asm volatile("" ::: "memory");
        __builtin_amdgcn_s_barrier();
    }

    // fused epilogue A
#pragma unroll
    for (int mi = 0; mi < 4; ++mi)
#pragma unroll
        for (int jj = 0; jj < 4; ++jj) {
            int row = m0 + wr + mi * 16 + fq * 4 + jj;
            f32x4 c = *(const f32x4*)(coeffs + (size_t)row * 4);
            float cpa = c.x + c.w;
#pragma unroll
            for (int ni = 0; ni < 2; ++ni) {
                int col = n0 + wc + ni * 16 + fr;
                float pa = prev_a[(size_t)row * 1024 + 512 + col];
                float v = cpa * pa + c.y * acc0[mi][ni][jj] + c.z * acc1[mi][ni][jj];
                outA[(size_t)row * 1024 + 512 + col] = v;
                na1b[(size_t)row * 512 + col] = __builtin_bit_cast(u16, __float2bfloat16(v));
            }
        }
}

// ---------------- phase-2 fused GEMM (pipelined): b00, b10, b11 + epilogue B ----------------
__global__ __launch_bounds__(512, 2) void k_gemmB(
    const u16* __restrict__ Xb, const u16* __restrict__ pab,
    const u16* __restrict__ na1b, const u16* __restrict__ pb1b,
    const u16* __restrict__ w00, const u16* __restrict__ w10, const u16* __restrict__ w11,
    const float* __restrict__ prev_b, const float* __restrict__ coeffs,
    float* __restrict__ outB)
{
    __shared__ u16 lds[2][4][8192];   // per buffer: A + up to 3 B tiles (64 KB); dbuf 128 KB
    const int t = threadIdx.x;
    int raw = (int)blockIdx.x;
    int bid = (raw & 7) * 32 + (raw >> 3);
    const int m0 = (bid >> 2) * 128;
    const int n0 = (bid & 3) * 128;
    const int lane = t & 63, wv = t >> 6;
    const int wr = (wv >> 2) * 64, wc = (wv & 3) * 32;
    const int fr = lane & 15, fq = lane >> 4;

    f32x4 acc00[4][2] = {}, acc10[4][2] = {}, acc11[4][2] = {};

    // 32 steps: seg0 X->(w00,w10,w11); seg1 pa->(w00 hi); seg2 na1->(w10 hi, w00 hi2);
    // seg3 pb1->(w11 hi). na1 staged once, feeds acc10 AND acc00.
    auto stage_step = [&](int s, u16 (*buf)[8192]) {
        int cb = (s & 7) * 64;
        int seg = s >> 3;
        if (seg == 0) {                 // 8 loads/thr
            stage128(Xb + (size_t)m0 * 512 + cb, 512, buf[0], t);
            stage128(w00 + (size_t)n0 * 1536 + cb, 1536, buf[1], t);
            stage128(w10 + (size_t)n0 * 1024 + cb, 1024, buf[2], t);
            stage128(w11 + (size_t)n0 * 1024 + cb, 1024, buf[3], t);
        } else if (seg == 1) {          // 4 loads/thr
            stage128(pab + (size_t)m0 * 512 + cb, 512, buf[0], t);
            stage128(w00 + (size_t)n0 * 1536 + 512 + cb, 1536, buf[1], t);
        } else if (seg == 2) {          // 6 loads/thr
            stage128(na1b + (size_t)m0 * 512 + cb, 512, buf[0], t);
            stage128(w10 + (size_t)n0 * 1024 + 512 + cb, 1024, buf[1], t);
            stage128(w00 + (size_t)n0 * 1536 + 1024 + cb, 1536, buf[2], t);
        } else {                        // 4 loads/thr
            stage128(pb1b + (size_t)m0 * 512 + cb, 512, buf[0], t);
            stage128(w11 + (size_t)n0 * 1024 + 512 + cb, 1024, buf[1], t);
        }
    };

    stage_step(0, lds[0]);
    for (int s = 0; s < 32; ++s) {
        int cur = s & 1;
        if (s + 1 < 32) {
            stage_step(s + 1, lds[cur ^ 1]);
            int segn = (s + 1) >> 3;
            if (segn == 0) WAITVM(8);
            else if (segn == 2) WAITVM(6);
            else WAITVM(4);
        } else {
            WAITVM(0);
        }
        __builtin_amdgcn_s_barrier();
        asm volatile("" ::: "memory");
        u16 (*buf)[8192] = lds[cur];
        int seg = s >> 3;
        if (seg == 0) {
#pragma unroll
            for (int kk = 0; kk < 2; ++kk) {
                int ks = kk * 4 + fq;
                bf16x8 a[4], b0[2], b1[2], b2[2];
#pragma unroll
                for (int mi = 0; mi < 4; ++mi) a[mi] = ld_frag(buf[0], wr + mi * 16 + fr, ks);
#pragma unroll
                for (int ni = 0; ni < 2; ++ni) {
                    b0[ni] = ld_frag(buf[1], wc + ni * 16 + fr, ks);
                    b1[ni] = ld_frag(buf[2], wc + ni * 16 + fr, ks);
                    b2[ni] = ld_frag(buf[3], wc + ni * 16 + fr, ks);
                }
#pragma unroll
                for (int mi = 0; mi < 4; ++mi)
#pragma unroll
                    for (int ni = 0; ni < 2; ++ni) {
                        acc00[mi][ni] = MFMA(a[mi], b0[ni], acc00[mi][ni]);
                        acc10[mi][ni] = MFMA(a[mi], b1[ni], acc10[mi][ni]);
                        acc11[mi][ni] = MFMA(a[mi], b2[ni], acc11[mi][ni]);
                    }
            }
        } else if (seg == 1) {
#pragma unroll
            for (int kk = 0; kk < 2; ++kk) {
                int ks = kk * 4 + fq;
                bf16x8 a[4], b0[2];
#pragma unroll
                for (int mi = 0; mi < 4; ++mi) a[mi] = ld_frag(buf[0], wr + mi * 16 + fr, ks);
#pragma unroll
                for (int ni = 0; ni < 2; ++ni) b0[ni] = ld_frag(buf[1], wc + ni * 16 + fr, ks);
#pragma unroll
                for (int mi = 0; mi < 4; ++mi)
#pragma unroll
                    for (int ni = 0; ni < 2; ++ni)
                        acc00[mi][ni] = MFMA(a[mi], b0[ni], acc00[mi][ni]);
            }
        } else if (seg == 2) {
#pragma unroll
            for (int kk = 0; kk < 2; ++kk) {
                int ks = kk * 4 + fq;
                bf16x8 a[4], b0[2], b1[2];
#pragma unroll
                for (int mi = 0; mi < 4; ++mi) a[mi] = ld_frag(buf[0], wr + mi * 16 + fr, ks);
#pragma unroll
                for (int ni = 0; ni < 2; ++ni) {
                    b0[ni] = ld_frag(buf[1], wc + ni * 16 + fr, ks);
                    b1[ni] = ld_frag(buf[2], wc + ni * 16 + fr, ks);
                }
#pragma unroll
                for (int mi = 0; mi < 4; ++mi)
#pragma unroll
                    for (int ni = 0; ni < 2; ++ni) {
                        acc10[mi][ni] = MFMA(a[mi], b0[ni], acc10[mi][ni]);
                        acc00[mi][ni] = MFMA(a[mi], b1[ni], acc00[mi][ni]);
                    }
            }
        } else {
#pragma unroll
            for (int kk = 0; kk < 2; ++kk) {
                int ks = kk * 4 + fq;
                bf16x8 a[4], b0[2];
#pragma unroll
                for (int mi = 0; mi < 4; ++mi) a[mi] = ld_frag(buf[0], wr + mi * 16 + fr, ks);
#pragma unroll
                for (int ni = 0; ni < 2; ++ni) b0[ni] = ld_frag(buf[1], wc + ni * 16 + fr, ks);
#pragma unroll
                for (int mi = 0; mi < 4; ++mi)
#pragma unroll
                    for (int ni = 0; ni < 2; ++ni)
                        acc11[mi][ni] = MFMA(a[mi], b0[ni], acc11[mi][ni]);
            }
        }
        asm volatile("" ::: "memory");
        __builtin_amdgcn_s_barrier();
    }

    // fused epilogue B
#pragma unroll
    for (int mi = 0; mi < 4; ++mi)
#pragma unroll
        for (int jj = 0; jj < 4; ++jj) {
            int row = m0 + wr + mi * 16 + fq * 4 + jj;
            f32x4 c = *(const f32x4*)(coeffs + (size_t)row * 4);
#pragma unroll
            for (int ni = 0; ni < 2; ++ni) {
                int col = n0 + wc + ni * 16 + fr;
                float pb1 = prev_b[(size_t)row * 1024 + 512 + col];
                float v = c.x * acc11[mi][ni][jj] + c.y * acc00[mi][ni][jj]
                        + c.z * acc10[mi][ni][jj] + c.w * pb1;
                outB[(size_t)row * 1024 + 512 + col] = v;
            }
        }
}

extern "C" void kernel_launch(void* const* d_in, const int* in_sizes, int n_in,
                              void* d_out, int out_size, void* d_ws, size_t ws_size,
                              hipStream_t stream) {
    const float* X          = (const float*)d_in[0];
    const float* prev_a     = (const float*)d_in[1];
    const float* prev_b     = (const float*)d_in[2];
    const int*   prev_depth = (const int*)d_in[3];
    const float* w_f        = (const float*)d_in[4];
    const float* w_a00      = (const float*)d_in[5];
    const float* w_a10      = (const float*)d_in[6];
    const float* w_b00      = (const float*)d_in[7];
    const float* w_b11      = (const float*)d_in[8];
    const float* w_b10      = (const float*)d_in[9];

    float* out  = (float*)d_out;
    float* outA = out;
    float* outB = out + 8388608;
    float* outD = out + 16777216;
    float* outF = outD + 8192;
    float* outJ = outF + 8192;

    char* ws = (char*)d_ws;
    size_t off = 0;
    auto alloc = [&](size_t bytes) -> char* {
        char* p = ws + off;
        off += (bytes + 255) & ~(size_t)255;
        return p;
    };
    u16* Xb    = (u16*)alloc((size_t)B_DIM * 512 * 2);
    u16* pab   = (u16*)alloc((size_t)B_DIM * 512 * 2);
    u16* pb0b  = (u16*)alloc((size_t)B_DIM * 512 * 2);
    u16* pb1b  = (u16*)alloc((size_t)B_DIM * 512 * 2);
    u16* na1b  = (u16*)alloc((size_t)B_DIM * 512 * 2);
    u16* wa00b = (u16*)alloc((size_t)512 * 1024 * 2);
    u16* wa10b = (u16*)alloc((size_t)512 * 1024 * 2);
    u16* wb00b = (u16*)alloc((size_t)512 * 1536 * 2);
    u16* wb11b = (u16*)alloc((size_t)512 * 1024 * 2);
    u16* wb10b = (u16*)alloc((size_t)512 * 1024 * 2);
    float* coeffs = (float*)alloc((size_t)B_DIM * 16);
    int* flag = (int*)alloc(256);
    if (off > ws_size) return;

    k_flag<<<1, 1024, 0, stream>>>(prev_depth, flag);
    k_prep2<<<2048, 256, 0, stream>>>(X, prev_a, prev_b, prev_depth, w_f, flag,
                                      Xb, pab, pb0b, pb1b, coeffs, outA, outB,
                                      outD, outF, outJ);
    k_conv_w<<<2816, 256, 0, stream>>>(w_a00, w_a10, w_b00, w_b11, w_b10,
                                       wa00b, wa10b, wb00b, wb11b, wb10b);
    k_gemmA<<<256, 512, 0, stream>>>(Xb, pab, pb0b, wa00b, wa10b,
                                     prev_a, coeffs, outA, na1b);
    k_gemmB<<<256, 512, 0, stream>>>(Xb, pab, na1b, pb1b, wb00b, wb10b, wb11b,
                                     prev_b, coeffs, outB);
}

// Round 5
// 101.231 us; speedup vs baseline: 1.0862x; 1.0862x over previous
//
#include <hip/hip_runtime.h>
#include <hip/hip_bf16.h>

typedef __attribute__((ext_vector_type(8))) __bf16 bf16x8;
typedef __attribute__((ext_vector_type(4))) float f32x4;
typedef __attribute__((ext_vector_type(4))) unsigned short u16x4;
typedef unsigned short u16;

typedef __attribute__((address_space(1))) void gvoid;
typedef __attribute__((address_space(3))) void lvoid;

#define B_DIM 8192
#define H_DIM 512

#define MFMA(a, b, c) __builtin_amdgcn_mfma_f32_16x16x32_bf16((a), (b), (c), 0, 0, 0)

__device__ __forceinline__ u16x4 cvt4(f32x4 v) {
    u16x4 r;
    r.x = __builtin_bit_cast(u16, __float2bfloat16(v.x));
    r.y = __builtin_bit_cast(u16, __float2bfloat16(v.y));
    r.z = __builtin_bit_cast(u16, __float2bfloat16(v.z));
    r.w = __builtin_bit_cast(u16, __float2bfloat16(v.w));
    return r;
}

// Stage a 64x64 bf16 tile into LDS with XOR-swizzled SOURCE column (rule #21):
// LDS dest linear (global_load_lds requirement); LDS slot s of row r holds
// global slot s^(r&7); readers apply the same XOR (ld_frag).
// 512 threads: one 16B load per thread.
__device__ __forceinline__ void stage64(const u16* g, int ldg, u16* ls, int t) {
    int e = t * 8;
    int r = e >> 6;
    int slot = (e & 63) >> 3;
    int csrc = (slot ^ (r & 7)) << 3;
    __builtin_amdgcn_global_load_lds((gvoid*)(g + (size_t)r * ldg + csrc),
                                     (lvoid*)&ls[e], 16, 0, 0);
}

// 128x64 tile: two 16B loads per thread (512 threads).
__device__ __forceinline__ void stage128(const u16* g, int ldg, u16* ls, int t) {
#pragma unroll
    for (int it = 0; it < 2; ++it) {
        int e = it * 4096 + t * 8;
        int r = e >> 6;
        int slot = (e & 63) >> 3;
        int csrc = (slot ^ (r & 7)) << 3;
        __builtin_amdgcn_global_load_lds((gvoid*)(g + (size_t)r * ldg + csrc),
                                         (lvoid*)&ls[e], 16, 0, 0);
    }
}

__device__ __forceinline__ bf16x8 ld_frag(const u16* ls, int row, int kslot) {
    return *(const bf16x8*)&ls[row * 64 + ((kslot ^ (row & 7)) << 3)];
}

// ---------------- all_zero flag ----------------
__global__ void k_flag(const int* __restrict__ pd, int* __restrict__ flag) {
    __shared__ int s;
    if (threadIdx.x == 0) s = 0;
    __syncthreads();
    int any = 0;
    for (int i = threadIdx.x; i < B_DIM; i += 1024) any |= pd[i];
    if (any) atomicOr(&s, 1);
    __syncthreads();
    if (threadIdx.x == 0) flag[0] = (s == 0) ? 1 : 0;
}

// ---------------- fused prep ----------------
__global__ void k_prep2(const float* __restrict__ X, const float* __restrict__ prev_a,
                        const float* __restrict__ prev_b, const int* __restrict__ prev_depth,
                        const float* __restrict__ w_f, const int* __restrict__ flag,
                        u16* __restrict__ Xb, u16* __restrict__ pab,
                        u16* __restrict__ pb0b, u16* __restrict__ pb1b,
                        float* __restrict__ coeffs, float* __restrict__ outA,
                        float* __restrict__ outB, float* __restrict__ outD,
                        float* __restrict__ outF, float* __restrict__ outJ) {
    int wv = threadIdx.x >> 6, l = threadIdx.x & 63;
    int row = blockIdx.x * 4 + wv;
    size_t r512 = (size_t)row * 512, r1024 = (size_t)row * 1024;
    int i = l * 8;
    f32x4 x0  = *(const f32x4*)(X + r512 + i);
    f32x4 x1  = *(const f32x4*)(X + r512 + i + 4);
    f32x4 pa0 = *(const f32x4*)(prev_a + r1024 + 512 + i);
    f32x4 pa1 = *(const f32x4*)(prev_a + r1024 + 512 + i + 4);
    f32x4 q00 = *(const f32x4*)(prev_b + r1024 + i);
    f32x4 q01 = *(const f32x4*)(prev_b + r1024 + i + 4);
    f32x4 q10 = *(const f32x4*)(prev_b + r1024 + 512 + i);
    f32x4 q11 = *(const f32x4*)(prev_b + r1024 + 512 + i + 4);
    f32x4 w0  = *(const f32x4*)(w_f + i);
    f32x4 w1  = *(const f32x4*)(w_f + i + 4);
    int depth = prev_depth[row];
    f32x4 b0 = depth ? q10 : q00;
    f32x4 b1 = depth ? q11 : q01;
    float dot = b0.x*w0.x + b0.y*w0.y + b0.z*w0.z + b0.w*w0.w
              + b1.x*w1.x + b1.y*w1.y + b1.z*w1.z + b1.w*w1.w;
    for (int off = 32; off > 0; off >>= 1) dot += __shfl_xor(dot, off, 64);

    *(u16x4*)(Xb   + r512 + i)     = cvt4(x0);
    *(u16x4*)(Xb   + r512 + i + 4) = cvt4(x1);
    *(u16x4*)(pab  + r512 + i)     = cvt4(pa0);
    *(u16x4*)(pab  + r512 + i + 4) = cvt4(pa1);
    *(u16x4*)(pb0b + r512 + i)     = cvt4(q00);
    *(u16x4*)(pb0b + r512 + i + 4) = cvt4(q01);
    *(u16x4*)(pb1b + r512 + i)     = cvt4(q10);
    *(u16x4*)(pb1b + r512 + i + 4) = cvt4(q11);
    f32x4 z; z.x = 0.f; z.y = 0.f; z.z = 0.f; z.w = 0.f;
    *(f32x4*)(outA + r1024 + i)     = z;
    *(f32x4*)(outA + r1024 + i + 4) = z;
    *(f32x4*)(outB + r1024 + i)     = z;
    *(f32x4*)(outB + r1024 + i + 4) = z;

    if (l == 0) {
        int az = flag[0];
        float sg = 1.0f / (1.0f + expf(-dot));
        float fr = rintf(sg);
        float f = az ? 1.0f : fr;
        float j = az ? 0.0f : fr;
        int nd = depth + (int)(f - j);
        float eq = (nd == 1) ? 1.0f : 0.0f;
        float lt = (nd < 1) ? 1.0f : 0.0f;
        f32x4 c; c.x = eq * (f * j); c.y = eq * (1.0f - f) * (1.0f - j);
        c.z = eq * f * (1.0f - j); c.w = lt;
        *(f32x4*)(coeffs + (size_t)row * 4) = c;
        outD[row] = (float)nd;
        outF[row] = f;
        outJ[row] = j;
    }
}

// ---------------- convert all 5 weight matrices to bf16 ----------------
__global__ void k_conv_w(const float* __restrict__ wa00, const float* __restrict__ wa10,
                         const float* __restrict__ wb00, const float* __restrict__ wb11,
                         const float* __restrict__ wb10,
                         u16* __restrict__ oa00, u16* __restrict__ oa10,
                         u16* __restrict__ ob00, u16* __restrict__ ob11,
                         u16* __restrict__ ob10) {
    int t = blockIdx.x * 256 + threadIdx.x;
    const int S  = 512 * 1024 / 4;
    const int SB = 512 * 1536 / 4;
    const float* src; u16* dst; int off;
    if      (t < S)            { src = wa00; dst = oa00; off = t; }
    else if (t < 2 * S)        { src = wa10; dst = oa10; off = t - S; }
    else if (t < 2 * S + SB)   { src = wb00; dst = ob00; off = t - 2 * S; }
    else if (t < 3 * S + SB)   { src = wb11; dst = ob11; off = t - 2 * S - SB; }
    else if (t < 4 * S + SB)   { src = wb10; dst = ob10; off = t - 3 * S - SB; }
    else return;
    f32x4 v = *(const f32x4*)(src + (size_t)off * 4);
    *(u16x4*)(dst + (size_t)off * 4) = cvt4(v);
}

// ---------------- phase-1 fused GEMM: a00 & a10 + epilogue A ----------------
// 512 blocks (64x128 tile), 512 threads = 8 waves (2M x 4N), per-wave 32x32.
// Round-3 structure (verified) with doubled waves/CU: 2 blocks/CU x 8 waves
// = 16 waves/CU (4/SIMD) — cross-block/wave overlap hides barrier drains.
__global__ __launch_bounds__(512, 4) void k_gemmA(
    const u16* __restrict__ Xb, const u16* __restrict__ pab, const u16* __restrict__ pb0b,
    const u16* __restrict__ w0, const u16* __restrict__ w1,
    const float* __restrict__ prev_a, const float* __restrict__ coeffs,
    float* __restrict__ outA, u16* __restrict__ na1b)
{
    __shared__ u16 lsA0[64 * 64];
    __shared__ u16 lsA1[64 * 64];
    __shared__ u16 lsB0[128 * 64];
    __shared__ u16 lsB1[128 * 64];
    const int t = threadIdx.x;
    int raw = (int)blockIdx.x;
    int bid = (raw & 7) * 64 + (raw >> 3);   // XCD-contiguous chunks (512/8=64)
    const int m0 = (bid >> 2) * 64;
    const int n0 = (bid & 3) * 128;
    const int lane = t & 63, wv = t >> 6;
    const int wr = (wv >> 2) * 32, wc = (wv & 3) * 32;
    const int fr = lane & 15, fq = lane >> 4;

    f32x4 acc0[2][2] = {}, acc1[2][2] = {};

    // half 1: k in [0,512), A = X feeds both
    for (int kq = 0; kq < 8; ++kq) {
        int cb = kq * 64;
        stage64(Xb + (size_t)m0 * 512 + cb, 512, lsA0, t);
        stage128(w0 + (size_t)n0 * 1024 + cb, 1024, lsB0, t);
        stage128(w1 + (size_t)n0 * 1024 + cb, 1024, lsB1, t);
        __syncthreads();
#pragma unroll
        for (int kk = 0; kk < 2; ++kk) {
            int ks = kk * 4 + fq;
            bf16x8 a[2], b0[2], b1[2];
#pragma unroll
            for (int mi = 0; mi < 2; ++mi) a[mi] = ld_frag(lsA0, wr + mi * 16 + fr, ks);
#pragma unroll
            for (int ni = 0; ni < 2; ++ni) {
                b0[ni] = ld_frag(lsB0, wc + ni * 16 + fr, ks);
                b1[ni] = ld_frag(lsB1, wc + ni * 16 + fr, ks);
            }
#pragma unroll
            for (int mi = 0; mi < 2; ++mi)
#pragma unroll
                for (int ni = 0; ni < 2; ++ni) {
                    acc0[mi][ni] = MFMA(a[mi], b0[ni], acc0[mi][ni]);
                    acc1[mi][ni] = MFMA(a[mi], b1[ni], acc1[mi][ni]);
                }
        }
        __syncthreads();
    }
    // half 2: k in [512,1024): A0 = pa -> acc0, A1 = pb0 -> acc1
    for (int kq = 0; kq < 8; ++kq) {
        int cb = kq * 64;
        stage64(pab + (size_t)m0 * 512 + cb, 512, lsA0, t);
        stage64(pb0b + (size_t)m0 * 512 + cb, 512, lsA1, t);
        stage128(w0 + (size_t)n0 * 1024 + 512 + cb, 1024, lsB0, t);
        stage128(w1 + (size_t)n0 * 1024 + 512 + cb, 1024, lsB1, t);
        __syncthreads();
#pragma unroll
        for (int kk = 0; kk < 2; ++kk) {
            int ks = kk * 4 + fq;
            bf16x8 a0[2], a1[2], b0[2], b1[2];
#pragma unroll
            for (int mi = 0; mi < 2; ++mi) {
                a0[mi] = ld_frag(lsA0, wr + mi * 16 + fr, ks);
                a1[mi] = ld_frag(lsA1, wr + mi * 16 + fr, ks);
            }
#pragma unroll
            for (int ni = 0; ni < 2; ++ni) {
                b0[ni] = ld_frag(lsB0, wc + ni * 16 + fr, ks);
                b1[ni] = ld_frag(lsB1, wc + ni * 16 + fr, ks);
            }
#pragma unroll
            for (int mi = 0; mi < 2; ++mi)
#pragma unroll
                for (int ni = 0; ni < 2; ++ni) {
                    acc0[mi][ni] = MFMA(a0[mi], b0[ni], acc0[mi][ni]);
                    acc1[mi][ni] = MFMA(a1[mi], b1[ni], acc1[mi][ni]);
                }
        }
        __syncthreads();
    }
    // fused epilogue A
#pragma unroll
    for (int mi = 0; mi < 2; ++mi)
#pragma unroll
        for (int jj = 0; jj < 4; ++jj) {
            int row = m0 + wr + mi * 16 + fq * 4 + jj;
            f32x4 c = *(const f32x4*)(coeffs + (size_t)row * 4);
            float cpa = c.x + c.w;
#pragma unroll
            for (int ni = 0; ni < 2; ++ni) {
                int col = n0 + wc + ni * 16 + fr;
                float pa = prev_a[(size_t)row * 1024 + 512 + col];
                float v = cpa * pa + c.y * acc0[mi][ni][jj] + c.z * acc1[mi][ni][jj];
                outA[(size_t)row * 1024 + 512 + col] = v;
                na1b[(size_t)row * 512 + col] = __builtin_bit_cast(u16, __float2bfloat16(v));
            }
        }
}

// ---------------- phase-2 fused GEMM: b00, b10, b11 + epilogue B ----------------
__global__ __launch_bounds__(512, 4) void k_gemmB(
    const u16* __restrict__ Xb, const u16* __restrict__ pab,
    const u16* __restrict__ na1b, const u16* __restrict__ pb1b,
    const u16* __restrict__ w00, const u16* __restrict__ w10, const u16* __restrict__ w11,
    const float* __restrict__ prev_b, const float* __restrict__ coeffs,
    float* __restrict__ outB)
{
    __shared__ u16 lsA0[64 * 64];
    __shared__ u16 lsA1[64 * 64];
    __shared__ u16 lsA2[64 * 64];
    __shared__ u16 lsB0[128 * 64];
    __shared__ u16 lsB1[128 * 64];
    __shared__ u16 lsB2[128 * 64];
    const int t = threadIdx.x;
    int raw = (int)blockIdx.x;
    int bid = (raw & 7) * 64 + (raw >> 3);
    const int m0 = (bid >> 2) * 64;
    const int n0 = (bid & 3) * 128;
    const int lane = t & 63, wv = t >> 6;
    const int wr = (wv >> 2) * 32, wc = (wv & 3) * 32;
    const int fr = lane & 15, fq = lane >> 4;

    f32x4 acc00[2][2] = {}, acc10[2][2] = {}, acc11[2][2] = {};

    // half 1: k in [0,512), A = X for all three
    for (int kq = 0; kq < 8; ++kq) {
        int cb = kq * 64;
        stage64(Xb + (size_t)m0 * 512 + cb, 512, lsA0, t);
        stage128(w00 + (size_t)n0 * 1536 + cb, 1536, lsB0, t);
        stage128(w10 + (size_t)n0 * 1024 + cb, 1024, lsB1, t);
        stage128(w11 + (size_t)n0 * 1024 + cb, 1024, lsB2, t);
        __syncthreads();
#pragma unroll
        for (int kk = 0; kk < 2; ++kk) {
            int ks = kk * 4 + fq;
            bf16x8 a[2], b0[2], b1[2], b2[2];
#pragma unroll
            for (int mi = 0; mi < 2; ++mi) a[mi] = ld_frag(lsA0, wr + mi * 16 + fr, ks);
#pragma unroll
            for (int ni = 0; ni < 2; ++ni) {
                b0[ni] = ld_frag(lsB0, wc + ni * 16 + fr, ks);
                b1[ni] = ld_frag(lsB1, wc + ni * 16 + fr, ks);
                b2[ni] = ld_frag(lsB2, wc + ni * 16 + fr, ks);
            }
#pragma unroll
            for (int mi = 0; mi < 2; ++mi)
#pragma unroll
                for (int ni = 0; ni < 2; ++ni) {
                    acc00[mi][ni] = MFMA(a[mi], b0[ni], acc00[mi][ni]);
                    acc10[mi][ni] = MFMA(a[mi], b1[ni], acc10[mi][ni]);
                    acc11[mi][ni] = MFMA(a[mi], b2[ni], acc11[mi][ni]);
                }
        }
        __syncthreads();
    }
    // half 2: k in [512,1024): A0=pa->acc00, A1=na1->acc10, A2=pb1->acc11
    for (int kq = 0; kq < 8; ++kq) {
        int cb = kq * 64;
        stage64(pab + (size_t)m0 * 512 + cb, 512, lsA0, t);
        stage64(na1b + (size_t)m0 * 512 + cb, 512, lsA1, t);
        stage64(pb1b + (size_t)m0 * 512 + cb, 512, lsA2, t);
        stage128(w00 + (size_t)n0 * 1536 + 512 + cb, 1536, lsB0, t);
        stage128(w10 + (size_t)n0 * 1024 + 512 + cb, 1024, lsB1, t);
        stage128(w11 + (size_t)n0 * 1024 + 512 + cb, 1024, lsB2, t);
        __syncthreads();
#pragma unroll
        for (int kk = 0; kk < 2; ++kk) {
            int ks = kk * 4 + fq;
            bf16x8 a0[2], a1[2], a2[2], b0[2], b1[2], b2[2];
#pragma unroll
            for (int mi = 0; mi < 2; ++mi) {
                a0[mi] = ld_frag(lsA0, wr + mi * 16 + fr, ks);
                a1[mi] = ld_frag(lsA1, wr + mi * 16 + fr, ks);
                a2[mi] = ld_frag(lsA2, wr + mi * 16 + fr, ks);
            }
#pragma unroll
            for (int ni = 0; ni < 2; ++ni) {
                b0[ni] = ld_frag(lsB0, wc + ni * 16 + fr, ks);
                b1[ni] = ld_frag(lsB1, wc + ni * 16 + fr, ks);
                b2[ni] = ld_frag(lsB2, wc + ni * 16 + fr, ks);
            }
#pragma unroll
            for (int mi = 0; mi < 2; ++mi)
#pragma unroll
                for (int ni = 0; ni < 2; ++ni) {
                    acc00[mi][ni] = MFMA(a0[mi], b0[ni], acc00[mi][ni]);
                    acc10[mi][ni] = MFMA(a1[mi], b1[ni], acc10[mi][ni]);
                    acc11[mi][ni] = MFMA(a2[mi], b2[ni], acc11[mi][ni]);
                }
        }
        __syncthreads();
    }
    // half 3: k in [1024,1536): A = na1 -> acc00 only
    for (int kq = 0; kq < 8; ++kq) {
        int cb = kq * 64;
        stage64(na1b + (size_t)m0 * 512 + cb, 512, lsA0, t);
        stage128(w00 + (size_t)n0 * 1536 + 1024 + cb, 1536, lsB0, t);
        __syncthreads();
#pragma unroll
        for (int kk = 0; kk < 2; ++kk) {
            int ks = kk * 4 + fq;
            bf16x8 a[2], b0[2];
#pragma unroll
            for (int mi = 0; mi < 2; ++mi) a[mi] = ld_frag(lsA0, wr + mi * 16 + fr, ks);
#pragma unroll
            for (int ni = 0; ni < 2; ++ni) b0[ni] = ld_frag(lsB0, wc + ni * 16 + fr, ks);
#pragma unroll
            for (int mi = 0; mi < 2; ++mi)
#pragma unroll
                for (int ni = 0; ni < 2; ++ni)
                    acc00[mi][ni] = MFMA(a[mi], b0[ni], acc00[mi][ni]);
        }
        __syncthreads();
    }
    // fused epilogue B
#pragma unroll
    for (int mi = 0; mi < 2; ++mi)
#pragma unroll
        for (int jj = 0; jj < 4; ++jj) {
            int row = m0 + wr + mi * 16 + fq * 4 + jj;
            f32x4 c = *(const f32x4*)(coeffs + (size_t)row * 4);
#pragma unroll
            for (int ni = 0; ni < 2; ++ni) {
                int col = n0 + wc + ni * 16 + fr;
                float pb1 = prev_b[(size_t)row * 1024 + 512 + col];
                float v = c.x * acc11[mi][ni][jj] + c.y * acc00[mi][ni][jj]
                        + c.z * acc10[mi][ni][jj] + c.w * pb1;
                outB[(size_t)row * 1024 + 512 + col] = v;
            }
        }
}

extern "C" void kernel_launch(void* const* d_in, const int* in_sizes, int n_in,
                              void* d_out, int out_size, void* d_ws, size_t ws_size,
                              hipStream_t stream) {
    const float* X          = (const float*)d_in[0];
    const float* prev_a     = (const float*)d_in[1];
    const float* prev_b     = (const float*)d_in[2];
    const int*   prev_depth = (const int*)d_in[3];
    const float* w_f        = (const float*)d_in[4];
    const float* w_a00      = (const float*)d_in[5];
    const float* w_a10      = (const float*)d_in[6];
    const float* w_b00      = (const float*)d_in[7];
    const float* w_b11      = (const float*)d_in[8];
    const float* w_b10      = (const float*)d_in[9];

    float* out  = (float*)d_out;
    float* outA = out;
    float* outB = out + 8388608;
    float* outD = out + 16777216;
    float* outF = outD + 8192;
    float* outJ = outF + 8192;

    char* ws = (char*)d_ws;
    size_t off = 0;
    auto alloc = [&](size_t bytes) -> char* {
        char* p = ws + off;
        off += (bytes + 255) & ~(size_t)255;
        return p;
    };
    u16* Xb    = (u16*)alloc((size_t)B_DIM * 512 * 2);
    u16* pab   = (u16*)alloc((size_t)B_DIM * 512 * 2);
    u16* pb0b  = (u16*)alloc((size_t)B_DIM * 512 * 2);
    u16* pb1b  = (u16*)alloc((size_t)B_DIM * 512 * 2);
    u16* na1b  = (u16*)alloc((size_t)B_DIM * 512 * 2);
    u16* wa00b = (u16*)alloc((size_t)512 * 1024 * 2);
    u16* wa10b = (u16*)alloc((size_t)512 * 1024 * 2);
    u16* wb00b = (u16*)alloc((size_t)512 * 1536 * 2);
    u16* wb11b = (u16*)alloc((size_t)512 * 1024 * 2);
    u16* wb10b = (u16*)alloc((size_t)512 * 1024 * 2);
    float* coeffs = (float*)alloc((size_t)B_DIM * 16);
    int* flag = (int*)alloc(256);
    if (off > ws_size) return;

    k_flag<<<1, 1024, 0, stream>>>(prev_depth, flag);
    k_prep2<<<2048, 256, 0, stream>>>(X, prev_a, prev_b, prev_depth, w_f, flag,
                                      Xb, pab, pb0b, pb1b, coeffs, outA, outB,
                                      outD, outF, outJ);
    k_conv_w<<<2816, 256, 0, stream>>>(w_a00, w_a10, w_b00, w_b11, w_b10,
                                       wa00b, wa10b, wb00b, wb11b, wb10b);
    k_gemmA<<<512, 512, 0, stream>>>(Xb, pab, pb0b, wa00b, wa10b,
                                     prev_a, coeffs, outA, na1b);
    k_gemmB<<<512, 512, 0, stream>>>(Xb, pab, na1b, pb1b, wb00b, wb10b, wb11b,
                                     prev_b, coeffs, outB);
}